// Round 3
// baseline (782.318 us; speedup 1.0000x reference)
//
#include <hip/hip_runtime.h>
#include <math.h>

#define NQ 4096
#define NT 16384
#define DD 32
#define COLIDX 0
#define BIGF 1.0e10f
#define INFF __builtin_inff()

// Read a "bool" element from an input array whose storage width is unknown
// at compile time: w32==0 -> 1-byte bools, w32==1 -> int32 bools.
__device__ __forceinline__ int boolat(const void* p, long long idx, int w32) {
    if (w32) return ((const int*)p)[idx] != 0;
    return ((const unsigned char*)p)[idx] != 0;
}

// Per-block bool-width detect: nm == ~mk elementwise by construction.
__device__ __forceinline__ int detect_w32(const void* nm, const void* mk,
                                          int tid, int* s_bad) {
    if (tid == 0) *s_bad = 0;
    __syncthreads();
    const unsigned char* nm8 = (const unsigned char*)nm;
    const unsigned char* mk8 = (const unsigned char*)mk;
    int bad = 0;
    for (int b = tid; b < 4096; b += 256)
        if ((int)nm8[b] + (int)mk8[b] != 1) bad = 1;
    if (bad) atomicOr(s_bad, 1);
    __syncthreads();
    return *s_bad ? 1 : 0;
}

// ---------------------------------------------------------------------------
// prep1: 64 blocks x 256 threads — one thread per fit row t.
// ---------------------------------------------------------------------------
__global__ __launch_bounds__(256) void prep1_kernel(
    const void* __restrict__ nm, const void* __restrict__ mk,
    const float* __restrict__ fitX,
    int* __restrict__ wflag, float* __restrict__ partial,
    unsigned char* __restrict__ inmiss, unsigned char* __restrict__ pot8)
{
    __shared__ int s_bad;
    __shared__ float sc[256], sm[256];
    const int tid = threadIdx.x;
    const int w32 = detect_w32(nm, mk, tid, &s_bad);
    if (blockIdx.x == 0 && tid == 0) *wflag = w32;

    const int t = blockIdx.x * 256 + tid;          // 0..16383
    pot8[t] = (unsigned char)boolat(nm, (long long)t * DD + COLIDX, w32);

    float cs = 0.0f, ms = 0.0f;
    if (!boolat(mk, (long long)t * DD + COLIDX, w32)) {
        cs = fitX[(long long)t * DD + COLIDX];
        ms = 1.0f;
    }
    sc[tid] = cs; sm[tid] = ms;
    __syncthreads();
#pragma unroll
    for (int s = 128; s > 0; s >>= 1) {
        if (tid < s) { sc[tid] += sc[tid + s]; sm[tid] += sm[tid + s]; }
        __syncthreads();
    }
    if (tid == 0) { partial[blockIdx.x * 2] = sc[0]; partial[blockIdx.x * 2 + 1] = sm[0]; }

    if (t < NQ) inmiss[t] = 0;
}

// ---------------------------------------------------------------------------
// prep2: 1 block — scatter row_missing_idx, finalize col_mean.
// ---------------------------------------------------------------------------
__global__ __launch_bounds__(256) void prep2_kernel(
    const int* __restrict__ rmi, const float* __restrict__ partial,
    float* __restrict__ cmean, unsigned char* __restrict__ inmiss)
{
    const int tid = threadIdx.x;
    for (int i = tid; i < NQ; i += 256) {
        int r = rmi[i];
        if (r >= 0 && r < NQ) inmiss[r] = 1;
    }
    if (tid == 0) {
        float c = 0.0f, m = 0.0f;
        for (int b = 0; b < 64; ++b) { c += partial[2 * b]; m += partial[2 * b + 1]; }
        *cmean = c / (m > 0.0f ? m : 1.0f);
    }
}

// ---------------------------------------------------------------------------
// Packed-u64 top-5: key64 = (float_bits << 32) | index. Keys are positive
// floats, so u64 order == (key asc, index asc) — exact jax.lax.top_k
// tie-break, independent of insertion order.
// ---------------------------------------------------------------------------
typedef unsigned long long u64;

__device__ __forceinline__ u64 packkey(float key, unsigned idx) {
    return ((u64)__float_as_uint(key) << 32) | (u64)idx;
}

__device__ __forceinline__ void insert64(u64 k, u64 v[5]) {
    const bool c0 = k < v[0];
    const bool c1 = k < v[1];
    const bool c2 = k < v[2];
    const bool c3 = k < v[3];
    const bool c4 = k < v[4];
    v[4] = c4 ? (c3 ? v[3] : k) : v[4];
    v[3] = c3 ? (c2 ? v[2] : k) : v[3];
    v[2] = c2 ? (c1 ? v[1] : k) : v[2];
    v[1] = c1 ? (c0 ? v[0] : k) : v[1];
    v[0] = c0 ? k : v[0];
}

// ---------------------------------------------------------------------------
// Main kernel: one block per query row; phase-staggered row sweep.
// ---------------------------------------------------------------------------
__global__ __launch_bounds__(256) void impute_kernel(
    const float* __restrict__ X,
    const float* __restrict__ dist,
    const void* __restrict__ maskp,
    const void* __restrict__ mkfitp,
    const float* __restrict__ fitX,
    const int* __restrict__ dmap,
    const int* __restrict__ wflagp,
    const float* __restrict__ cmeanp,
    const unsigned char* __restrict__ inmiss,
    const unsigned char* __restrict__ pot8,
    float* __restrict__ out)
{
    const int i = blockIdx.x;
    const int tid = threadIdx.x;

    if (tid < DD)
        out[(long long)i * DD + tid] = X[(long long)i * DD + tid];

    const int q = dmap[i];
    const float4* drow = (const float4*)(dist + (long long)q * NT);
    const uchar4* prow = (const uchar4*)pot8;

    u64 v[5];
#pragma unroll
    for (int k = 0; k < 5; ++k) v[k] = 0xFFFFFFFFFFFFFFFFULL;

    // Phase stagger: block starts its sweep at a per-block phase so that
    // co-resident blocks cover different low-address windows of their rows
    // (defeats HBM channel hotspotting from 64KB-strided rows in lockstep).
    const int start = (i >> 3) & 15;

    float4 dA = drow[((start + 0) & 15) * 256 + tid];
    uchar4 cA = prow[((start + 0) & 15) * 256 + tid];
    float4 dB = drow[((start + 1) & 15) * 256 + tid];
    uchar4 cB = prow[((start + 1) & 15) * 256 + tid];

#pragma unroll 1
    for (int it = 0; it < 16; it += 2) {
        // ---- stage A (logical iter it) ----
        {
            const int ph = (start + it) & 15;
            const float4 dc = dA; const uchar4 cc = cA;
            if (it + 2 < 16) {
                const int ph2 = (start + it + 2) & 15;
                dA = drow[ph2 * 256 + tid];
                cA = prow[ph2 * 256 + tid];
            }
            const unsigned base = (unsigned)(ph * 256 + tid) * 4u;
            {
                const float key = (cc.x != 0) ? fminf(dc.x, BIGF) : INFF;
                insert64(packkey(key, base + 0), v);
            }
            {
                const float key = (cc.y != 0) ? fminf(dc.y, BIGF) : INFF;
                insert64(packkey(key, base + 1), v);
            }
            {
                const float key = (cc.z != 0) ? fminf(dc.z, BIGF) : INFF;
                insert64(packkey(key, base + 2), v);
            }
            {
                const float key = (cc.w != 0) ? fminf(dc.w, BIGF) : INFF;
                insert64(packkey(key, base + 3), v);
            }
        }
        // ---- stage B (logical iter it+1) ----
        {
            const int ph = (start + it + 1) & 15;
            const float4 dc = dB; const uchar4 cc = cB;
            if (it + 3 < 16) {
                const int ph2 = (start + it + 3) & 15;
                dB = drow[ph2 * 256 + tid];
                cB = prow[ph2 * 256 + tid];
            }
            const unsigned base = (unsigned)(ph * 256 + tid) * 4u;
            {
                const float key = (cc.x != 0) ? fminf(dc.x, BIGF) : INFF;
                insert64(packkey(key, base + 0), v);
            }
            {
                const float key = (cc.y != 0) ? fminf(dc.y, BIGF) : INFF;
                insert64(packkey(key, base + 1), v);
            }
            {
                const float key = (cc.z != 0) ? fminf(dc.z, BIGF) : INFF;
                insert64(packkey(key, base + 2), v);
            }
            {
                const float key = (cc.w != 0) ? fminf(dc.w, BIGF) : INFF;
                insert64(packkey(key, base + 3), v);
            }
        }
    }

    // wave-level merge (64 lanes -> lane 0)
#pragma unroll
    for (int off = 32; off >= 1; off >>= 1) {
        u64 v2[5];
#pragma unroll
        for (int k = 0; k < 5; ++k) v2[k] = __shfl_down(v[k], off);
#pragma unroll
        for (int k = 0; k < 5; ++k) insert64(v2[k], v);
    }

    __shared__ u64 sk[4][5];
    const int wave = tid >> 6;
    const int lane = tid & 63;
    if (lane == 0) {
#pragma unroll
        for (int k = 0; k < 5; ++k) sk[wave][k] = v[k];
    }
    __syncthreads();

    if (tid == 0) {
#pragma unroll
        for (int wv = 1; wv < 4; ++wv)
#pragma unroll
            for (int k = 0; k < 5; ++k) insert64(sk[wv][k], v);

        const int w32 = *wflagp;
        const bool has_valid =
            (unsigned)(v[0] >> 32) < __float_as_uint(BIGF);
        const bool receiver =
            inmiss[i] && boolat(maskp, (long long)i * DD + COLIDX, w32);

        float val;
        if (!receiver) {
            val = X[(long long)i * DD + COLIDX];
        } else if (!has_valid) {
            val = *cmeanp;
        } else {
            float keyf[5]; int idx[5]; bool ok[5]; int idxc[5];
#pragma unroll
            for (int k = 0; k < 5; ++k) {
                keyf[k] = __uint_as_float((unsigned)(v[k] >> 32));
                idx[k]  = (int)(unsigned)(v[k] & 0xFFFFFFFFu);
                ok[k]   = ((unsigned)idx[k]) < NT;
                idxc[k] = ok[k] ? idx[k] : 0;
            }
            // batched independent loads (one waitcnt, not 15 serialized)
            float dnr[5]; int mfv[5]; unsigned char vldb[5];
#pragma unroll
            for (int k = 0; k < 5; ++k)
                dnr[k] = fitX[(long long)idxc[k] * DD + COLIDX];
#pragma unroll
            for (int k = 0; k < 5; ++k)
                mfv[k] = boolat(mkfitp, (long long)idxc[k] * DD + COLIDX, w32);
#pragma unroll
            for (int k = 0; k < 5; ++k) vldb[k] = pot8[idxc[k]];

            float wk[5];
            bool infrow = false;
#pragma unroll
            for (int k = 0; k < 5; ++k) {
                const float dpot = (keyf[k] == BIGF) ? __builtin_nanf("") : keyf[k];
                const float t = 1.0f / dpot;       // 0->inf, inf->0, NaN->NaN
                wk[k] = ok[k] ? t : 0.0f;
                if (ok[k] && isinf(t)) infrow = true;
            }
            if (infrow) {
#pragma unroll
                for (int k = 0; k < 5; ++k) wk[k] = isinf(wk[k]) ? 1.0f : 0.0f;
            }
#pragma unroll
            for (int k = 0; k < 5; ++k) if (wk[k] != wk[k]) wk[k] = 0.0f;

            float wsum = 0.0f, vsum = 0.0f;
#pragma unroll
            for (int k = 0; k < 5; ++k) {
                const float dm = ok[k] ? (1.0f - (float)mfv[k]) : 0.0f;
                const float vl = ok[k] ? (float)vldb[k] : 0.0f;
                const float nw = dm * wk[k] * vl;
                wsum += nw;
                vsum += dnr[k] * nw;
            }
            const float div = (wsum == 0.0f) ? 1.0f : wsum;
            val = vsum / div;
        }
        out[(long long)i * DD + COLIDX] = val;
    }
}

extern "C" void kernel_launch(void* const* d_in, const int* in_sizes, int n_in,
                              void* d_out, int out_size, void* d_ws, size_t ws_size,
                              hipStream_t stream) {
    const float* X     = (const float*)d_in[0];
    const float* dist  = (const float*)d_in[1];
    const void*  nm    = d_in[2];   // non_missing_fix_X (bool)
    const void*  mkfit = d_in[3];   // mask_fit_X (bool)
    const int*   dmap  = (const int*)d_in[4];
    const void*  maskp = d_in[5];   // mask (bool)
    const int*   rmi   = (const int*)d_in[6];
    const float* fitX  = (const float*)d_in[7];
    float* out = (float*)d_out;

    int*   wflag   = (int*)d_ws;
    float* cmean   = (float*)((char*)d_ws + 4);
    float* partial = (float*)((char*)d_ws + 8);              // 64*2 floats
    unsigned char* inmiss = (unsigned char*)d_ws + 520;      // NQ bytes
    unsigned char* pot8   = (unsigned char*)d_ws + 520 + NQ; // NT bytes, 4-aligned

    prep1_kernel<<<64, 256, 0, stream>>>(nm, mkfit, fitX, wflag, partial, inmiss, pot8);
    prep2_kernel<<<1, 256, 0, stream>>>(rmi, partial, cmean, inmiss);
    impute_kernel<<<NQ, 256, 0, stream>>>(X, dist, maskp, mkfit, fitX, dmap,
                                          wflag, cmean, inmiss, pot8, out);
}

// Round 4
// 421.512 us; speedup vs baseline: 1.8560x; 1.8560x over previous
//
#include <hip/hip_runtime.h>
#include <math.h>

#define NQ 4096
#define NT 16384
#define DD 32
#define COLIDX 0
#define BIGF 1.0e10f
#define INFF __builtin_inff()

// Read a "bool" element from an input array whose storage width is unknown
// at compile time: w32==0 -> 1-byte bools, w32==1 -> int32 bools.
__device__ __forceinline__ int boolat(const void* p, long long idx, int w32) {
    if (w32) return ((const int*)p)[idx] != 0;
    return ((const unsigned char*)p)[idx] != 0;
}

// Per-block bool-width detect: nm == ~mk elementwise by construction.
__device__ __forceinline__ int detect_w32(const void* nm, const void* mk,
                                          int tid, int* s_bad) {
    if (tid == 0) *s_bad = 0;
    __syncthreads();
    const unsigned char* nm8 = (const unsigned char*)nm;
    const unsigned char* mk8 = (const unsigned char*)mk;
    int bad = 0;
    for (int b = tid; b < 4096; b += 256)
        if ((int)nm8[b] + (int)mk8[b] != 1) bad = 1;
    if (bad) atomicOr(s_bad, 1);
    __syncthreads();
    return *s_bad ? 1 : 0;
}

// ---------------------------------------------------------------------------
// prep1: 64 blocks x 256 threads — one thread per fit row t.
// ---------------------------------------------------------------------------
__global__ __launch_bounds__(256) void prep1_kernel(
    const void* __restrict__ nm, const void* __restrict__ mk,
    const float* __restrict__ fitX,
    int* __restrict__ wflag, float* __restrict__ partial,
    unsigned char* __restrict__ inmiss, unsigned char* __restrict__ pot8)
{
    __shared__ int s_bad;
    __shared__ float sc[256], sm[256];
    const int tid = threadIdx.x;
    const int w32 = detect_w32(nm, mk, tid, &s_bad);
    if (blockIdx.x == 0 && tid == 0) *wflag = w32;

    const int t = blockIdx.x * 256 + tid;          // 0..16383
    pot8[t] = (unsigned char)boolat(nm, (long long)t * DD + COLIDX, w32);

    float cs = 0.0f, ms = 0.0f;
    if (!boolat(mk, (long long)t * DD + COLIDX, w32)) {
        cs = fitX[(long long)t * DD + COLIDX];
        ms = 1.0f;
    }
    sc[tid] = cs; sm[tid] = ms;
    __syncthreads();
#pragma unroll
    for (int s = 128; s > 0; s >>= 1) {
        if (tid < s) { sc[tid] += sc[tid + s]; sm[tid] += sm[tid + s]; }
        __syncthreads();
    }
    if (tid == 0) { partial[blockIdx.x * 2] = sc[0]; partial[blockIdx.x * 2 + 1] = sm[0]; }

    if (t < NQ) inmiss[t] = 0;
}

// ---------------------------------------------------------------------------
// prep2: 1 block — scatter row_missing_idx, finalize col_mean.
// ---------------------------------------------------------------------------
__global__ __launch_bounds__(256) void prep2_kernel(
    const int* __restrict__ rmi, const float* __restrict__ partial,
    float* __restrict__ cmean, unsigned char* __restrict__ inmiss)
{
    const int tid = threadIdx.x;
    for (int i = tid; i < NQ; i += 256) {
        int r = rmi[i];
        if (r >= 0 && r < NQ) inmiss[r] = 1;
    }
    if (tid == 0) {
        float c = 0.0f, m = 0.0f;
        for (int b = 0; b < 64; ++b) { c += partial[2 * b]; m += partial[2 * b + 1]; }
        *cmean = c / (m > 0.0f ? m : 1.0f);
    }
}

// ---------------------------------------------------------------------------
// Branchless top-5 maintenance (f32 keys + i32 ids; compile-time indices).
// ---------------------------------------------------------------------------
// Strict <: among equal keys, keeps the first-inserted. Exact-key ties among
// real distances are ~5e-9/row; INF/BIG ties carry zero weight downstream.
__device__ __forceinline__ void insert_scan(float key, int t, float v[5], int id[5]) {
    const bool c0 = key < v[0];
    const bool c1 = key < v[1];
    const bool c2 = key < v[2];
    const bool c3 = key < v[3];
    const bool c4 = key < v[4];
    v[4] = c4 ? (c3 ? v[3] : key) : v[4];  id[4] = c4 ? (c3 ? id[3] : t) : id[4];
    v[3] = c3 ? (c2 ? v[2] : key) : v[3];  id[3] = c3 ? (c2 ? id[2] : t) : id[3];
    v[2] = c2 ? (c1 ? v[1] : key) : v[2];  id[2] = c2 ? (c1 ? id[1] : t) : id[2];
    v[1] = c1 ? (c0 ? v[0] : key) : v[1];  id[1] = c1 ? (c0 ? id[0] : t) : id[1];
    v[0] = c0 ? key : v[0];                id[0] = c0 ? t : id[0];
}

// Merge insert with full tie-break (lower index wins on equal key).
__device__ __forceinline__ void insert_merge(float key, int t, float v[5], int id[5]) {
    const bool c0 = (key < v[0]) || (key == v[0] && t < id[0]);
    const bool c1 = (key < v[1]) || (key == v[1] && t < id[1]);
    const bool c2 = (key < v[2]) || (key == v[2] && t < id[2]);
    const bool c3 = (key < v[3]) || (key == v[3] && t < id[3]);
    const bool c4 = (key < v[4]) || (key == v[4] && t < id[4]);
    v[4] = c4 ? (c3 ? v[3] : key) : v[4];  id[4] = c4 ? (c3 ? id[3] : t) : id[4];
    v[3] = c3 ? (c2 ? v[2] : key) : v[3];  id[3] = c3 ? (c2 ? id[2] : t) : id[3];
    v[2] = c2 ? (c1 ? v[1] : key) : v[2];  id[2] = c2 ? (c1 ? id[1] : t) : id[2];
    v[1] = c1 ? (c0 ? v[0] : key) : v[1];  id[1] = c1 ? (c0 ? id[0] : t) : id[1];
    v[0] = c0 ? key : v[0];                id[0] = c0 ? t : id[0];
}

// ---------------------------------------------------------------------------
// Main kernel: one block (256 thr) per query row. Identical to round-2
// structure except the 4KB window order is XOR-permuted per block so that
// co-resident blocks cover different low-address windows (defeats HBM
// channel/bank hotspotting from 64KB-strided rows scanned in lockstep).
// ---------------------------------------------------------------------------
__global__ __launch_bounds__(256) void impute_kernel(
    const float* __restrict__ X,
    const float* __restrict__ dist,
    const void* __restrict__ maskp,
    const void* __restrict__ mkfitp,
    const float* __restrict__ fitX,
    const int* __restrict__ dmap,
    const int* __restrict__ wflagp,
    const float* __restrict__ cmeanp,
    const unsigned char* __restrict__ inmiss,
    const unsigned char* __restrict__ pot8,
    float* __restrict__ out)
{
    const int i = blockIdx.x;
    const int tid = threadIdx.x;

    if (tid < DD)
        out[(long long)i * DD + tid] = X[(long long)i * DD + tid];

    const int q = dmap[i];
    const float4* drow = (const float4*)(dist + (long long)q * NT);
    const uchar4* prow = (const uchar4*)pot8;

    // Window permutation: uniform over 16 phases chip-wide AND within each
    // XCD (blocks round-robin XCDs by blockIdx & 7).
    const int bxor = (i ^ (i >> 3)) & 15;

    float v[5]; int id[5];
#pragma unroll
    for (int k = 0; k < 5; ++k) { v[k] = INFF; id[k] = 0x7fffffff; }

    float4 dv0 = drow[((0 ^ bxor) * 256) + tid];
    uchar4 pv0 = prow[((0 ^ bxor) * 256) + tid];
    float4 dv1 = drow[((1 ^ bxor) * 256) + tid];
    uchar4 pv1 = prow[((1 ^ bxor) * 256) + tid];

#pragma unroll
    for (int it = 0; it < 16; ++it) {
        const float4 dc = dv0; const uchar4 pc = pv0;
        dv0 = dv1; pv0 = pv1;
        if (it < 14) {
            const int w2 = ((it + 2) ^ bxor) * 256 + tid;
            dv1 = drow[w2];
            pv1 = prow[w2];
        }
        const int base = ((it ^ bxor) * 256 + tid) * 4;
        const float dj[4] = { dc.x, dc.y, dc.z, dc.w };
        const unsigned char pj[4] = { pc.x, pc.y, pc.z, pc.w };
#pragma unroll
        for (int j = 0; j < 4; ++j) {
            // fminf maps NaN -> BIGF (v_min_f32 returns non-NaN operand);
            // pot-false -> +inf.
            const float key = (pj[j] != 0) ? fminf(dj[j], BIGF) : INFF;
            insert_scan(key, base + j, v, id);
        }
    }

    // wave-level merge (64 lanes -> lane 0)
#pragma unroll
    for (int off = 32; off >= 1; off >>= 1) {
        float v2[5]; int id2[5];
#pragma unroll
        for (int k = 0; k < 5; ++k) {
            v2[k] = __shfl_down(v[k], off);
            id2[k] = __shfl_down(id[k], off);
        }
#pragma unroll
        for (int k = 0; k < 5; ++k) insert_merge(v2[k], id2[k], v, id);
    }

    __shared__ float sv[4][5];
    __shared__ int   sid[4][5];
    const int wave = tid >> 6;
    const int lane = tid & 63;
    if (lane == 0) {
#pragma unroll
        for (int k = 0; k < 5; ++k) { sv[wave][k] = v[k]; sid[wave][k] = id[k]; }
    }
    __syncthreads();

    if (tid == 0) {
#pragma unroll
        for (int wv = 1; wv < 4; ++wv)
#pragma unroll
            for (int k = 0; k < 5; ++k) insert_merge(sv[wv][k], sid[wv][k], v, id);

        const int w32 = *wflagp;
        const bool has_valid = v[0] < BIGF;   // some pot && !nan element seen
        const bool receiver =
            inmiss[i] && boolat(maskp, (long long)i * DD + COLIDX, w32);

        float val;
        if (!receiver) {
            val = X[(long long)i * DD + COLIDX];
        } else if (!has_valid) {
            val = *cmeanp;
        } else {
            bool ok[5]; int idxc[5];
#pragma unroll
            for (int k = 0; k < 5; ++k) {
                ok[k]   = ((unsigned)id[k]) < NT;
                idxc[k] = ok[k] ? id[k] : 0;
            }
            // batched independent loads
            float dnr[5]; int mfv[5]; unsigned char vldb[5];
#pragma unroll
            for (int k = 0; k < 5; ++k)
                dnr[k] = fitX[(long long)idxc[k] * DD + COLIDX];
#pragma unroll
            for (int k = 0; k < 5; ++k)
                mfv[k] = boolat(mkfitp, (long long)idxc[k] * DD + COLIDX, w32);
#pragma unroll
            for (int k = 0; k < 5; ++k) vldb[k] = pot8[idxc[k]];

            float wk[5];
            bool infrow = false;
#pragma unroll
            for (int k = 0; k < 5; ++k) {
                const float dpot = (v[k] == BIGF) ? __builtin_nanf("") : v[k];
                const float t = 1.0f / dpot;       // 0->inf, inf->0, NaN->NaN
                wk[k] = ok[k] ? t : 0.0f;
                if (ok[k] && isinf(t)) infrow = true;
            }
            if (infrow) {
#pragma unroll
                for (int k = 0; k < 5; ++k) wk[k] = isinf(wk[k]) ? 1.0f : 0.0f;
            }
#pragma unroll
            for (int k = 0; k < 5; ++k) if (wk[k] != wk[k]) wk[k] = 0.0f;

            float wsum = 0.0f, vsum = 0.0f;
#pragma unroll
            for (int k = 0; k < 5; ++k) {
                const float dm = ok[k] ? (1.0f - (float)mfv[k]) : 0.0f;
                const float vl = ok[k] ? (float)vldb[k] : 0.0f;
                const float nw = dm * wk[k] * vl;
                wsum += nw;
                vsum += dnr[k] * nw;
            }
            const float div = (wsum == 0.0f) ? 1.0f : wsum;
            val = vsum / div;
        }
        out[(long long)i * DD + COLIDX] = val;
    }
}

extern "C" void kernel_launch(void* const* d_in, const int* in_sizes, int n_in,
                              void* d_out, int out_size, void* d_ws, size_t ws_size,
                              hipStream_t stream) {
    const float* X     = (const float*)d_in[0];
    const float* dist  = (const float*)d_in[1];
    const void*  nm    = d_in[2];   // non_missing_fix_X (bool)
    const void*  mkfit = d_in[3];   // mask_fit_X (bool)
    const int*   dmap  = (const int*)d_in[4];
    const void*  maskp = d_in[5];   // mask (bool)
    const int*   rmi   = (const int*)d_in[6];
    const float* fitX  = (const float*)d_in[7];
    float* out = (float*)d_out;

    int*   wflag   = (int*)d_ws;
    float* cmean   = (float*)((char*)d_ws + 4);
    float* partial = (float*)((char*)d_ws + 8);              // 64*2 floats
    unsigned char* inmiss = (unsigned char*)d_ws + 520;      // NQ bytes
    unsigned char* pot8   = (unsigned char*)d_ws + 520 + NQ; // NT bytes, 4-aligned

    prep1_kernel<<<64, 256, 0, stream>>>(nm, mkfit, fitX, wflag, partial, inmiss, pot8);
    prep2_kernel<<<1, 256, 0, stream>>>(rmi, partial, cmean, inmiss);
    impute_kernel<<<NQ, 256, 0, stream>>>(X, dist, maskp, mkfit, fitX, dmap,
                                          wflag, cmean, inmiss, pot8, out);
}